// Round 7
// baseline (790.687 us; speedup 1.0000x reference)
//
#include <hip/hip_runtime.h>
#include <math.h>

#define N_ATOMS 50000
#define N_RES 6250
#define C_IN 30
#define E_DIM 12
#define E_BOND 150000
#define E_RAD 800000
#define E_RES_RAD 400000
#define E_CORR 20000

__device__ __forceinline__ int rfl(int v) { return __builtin_amdgcn_readfirstlane(v); }

// ---------------- generic row matvec: out[r][0:64] = X[r][0:K] @ W[K][64] ----------------
template <int K>
__global__ void rowmat64(const float* __restrict__ X, const float* __restrict__ W,
                         float* __restrict__ out, int nrows) {
  const int lane = threadIdx.x & 63;
  const int wid = (blockIdx.x * blockDim.x + threadIdx.x) >> 6;
  const int nw = (gridDim.x * blockDim.x) >> 6;
  float wcol[K];
#pragma unroll
  for (int k = 0; k < K; k++) wcol[k] = W[k * 64 + lane];
  for (int r = wid; r < nrows; r += nw) {
    float acc = 0.0f;
#pragma unroll
    for (int k = 0; k < K; k++) acc += X[(size_t)r * K + k] * wcol[k];
    out[(size_t)r * 64 + lane] = acc;
  }
}

// ---------------- CSR build: histogram / single-block exclusive scan / scatter ----------------
__global__ void hist_kernel(const int* __restrict__ dst, int* __restrict__ cnt, int n) {
  int i = blockIdx.x * blockDim.x + threadIdx.x;
  if (i < n) atomicAdd(&cnt[dst[i]], 1);
}

// exclusive scan of cnt[0:n] -> cur[0:n]; single block of 1024 threads, loop with carry
__global__ void ex_scan(const int* __restrict__ cnt, int* __restrict__ cur, int n) {
  __shared__ int wsums[16];
  __shared__ int carry_s;
  const int tid = threadIdx.x;
  const int lane = tid & 63;
  const int w = tid >> 6;
  if (tid == 0) carry_s = 0;
  __syncthreads();
  for (int base = 0; base < n; base += 1024) {
    int i = base + tid;
    int v = (i < n) ? cnt[i] : 0;
    int s = v;
#pragma unroll
    for (int m = 1; m < 64; m <<= 1) {
      int t = __shfl_up(s, m, 64);
      if (lane >= m) s += t;
    }
    if (lane == 63) wsums[w] = s;
    __syncthreads();
    if (w == 0) {
      int x = (lane < 16) ? wsums[lane] : 0;
#pragma unroll
      for (int m = 1; m < 16; m <<= 1) {
        int t = __shfl_up(x, m, 64);
        if (lane >= m) x += t;
      }
      if (lane < 16) wsums[lane] = x;
    }
    __syncthreads();
    const int woff = (w > 0) ? wsums[w - 1] : 0;
    const int carry = carry_s;
    if (i < n) cur[i] = carry + woff + (s - v);  // exclusive
    __syncthreads();
    if (tid == 1023) carry_s = carry + wsums[15];
    __syncthreads();
  }
}

// scatter: cur[d] walks from start(d) to end(d); afterwards cur[d] == end(d), start(d)=cur[d-1]
__global__ void scat_kernel(const int* __restrict__ src, const int* __restrict__ dst,
                            int* __restrict__ cur, int* __restrict__ ss, int n) {
  int e = blockIdx.x * blockDim.x + threadIdx.x;
  if (e < n) {
    int p = atomicAdd(&cur[dst[e]], 1);
    ss[p] = src[e];
  }
}

// ---------------- PointConv1 gather: one wave per atom, no atomics ----------------
__global__ void pc1_gather(const float* __restrict__ xw1, const float* __restrict__ pos,
                           const int* __restrict__ ss, const int* __restrict__ cur,
                           const float* __restrict__ W, const float* __restrict__ b,
                           const float* __restrict__ g, const float* __restrict__ be,
                           float* __restrict__ acc) {
  const int lane = threadIdx.x & 63;
  const int d = (blockIdx.x * blockDim.x + threadIdx.x) >> 6;
  if (d >= N_ATOMS) return;
  const float w0 = W[(C_IN + 0) * 64 + lane];
  const float w1 = W[(C_IN + 1) * 64 + lane];
  const float w2 = W[(C_IN + 2) * 64 + lane];
  const float bb = b[lane], gg = g[lane], eb = be[lane];
  const int beg = rfl(d ? cur[d - 1] : 0);
  const int end = rfl(cur[d]);
  const float pd0 = pos[d * 3 + 0], pd1 = pos[d * 3 + 1], pd2 = pos[d * 3 + 2];
  // self loop: dp = 0
  float h = fmaxf(xw1[(size_t)d * 64 + lane] + bb, 0.0f);
  float s1 = h, s2 = h * h;
#pragma unroll
  for (int m = 1; m < 64; m <<= 1) {
    s1 += __shfl_xor(s1, m, 64);
    s2 += __shfl_xor(s2, m, 64);
  }
  float mu = s1 * (1.0f / 64.0f);
  float var = s2 * (1.0f / 64.0f) - mu * mu;
  float accv = (h - mu) * rsqrtf(var + 1e-5f) * gg + eb;
  int j = beg;
  for (; j + 1 < end; j += 2) {
    const int sA = rfl(ss[j]);
    const int sB = rfl(ss[j + 1]);
    const float dA0 = pos[sA * 3 + 0] - pd0, dA1 = pos[sA * 3 + 1] - pd1,
                dA2 = pos[sA * 3 + 2] - pd2;
    const float dB0 = pos[sB * 3 + 0] - pd0, dB1 = pos[sB * 3 + 1] - pd1,
                dB2 = pos[sB * 3 + 2] - pd2;
    float hA = fmaxf(xw1[(size_t)sA * 64 + lane] + bb + dA0 * w0 + dA1 * w1 + dA2 * w2, 0.0f);
    float hB = fmaxf(xw1[(size_t)sB * 64 + lane] + bb + dB0 * w0 + dB1 * w1 + dB2 * w2, 0.0f);
    float s1A = hA, s2A = hA * hA, s1B = hB, s2B = hB * hB;
#pragma unroll
    for (int m = 1; m < 64; m <<= 1) {
      s1A += __shfl_xor(s1A, m, 64);
      s2A += __shfl_xor(s2A, m, 64);
      s1B += __shfl_xor(s1B, m, 64);
      s2B += __shfl_xor(s2B, m, 64);
    }
    const float muA = s1A * (1.0f / 64.0f), muB = s1B * (1.0f / 64.0f);
    const float vaA = s2A * (1.0f / 64.0f) - muA * muA;
    const float vaB = s2B * (1.0f / 64.0f) - muB * muB;
    accv += (hA - muA) * rsqrtf(vaA + 1e-5f) * gg + eb;
    accv += (hB - muB) * rsqrtf(vaB + 1e-5f) * gg + eb;
  }
  if (j < end) {
    const int sA = rfl(ss[j]);
    const float dA0 = pos[sA * 3 + 0] - pd0, dA1 = pos[sA * 3 + 1] - pd1,
                dA2 = pos[sA * 3 + 2] - pd2;
    float hA = fmaxf(xw1[(size_t)sA * 64 + lane] + bb + dA0 * w0 + dA1 * w1 + dA2 * w2, 0.0f);
    float s1A = hA, s2A = hA * hA;
#pragma unroll
    for (int m = 1; m < 64; m <<= 1) {
      s1A += __shfl_xor(s1A, m, 64);
      s2A += __shfl_xor(s2A, m, 64);
    }
    const float muA = s1A * (1.0f / 64.0f);
    const float vaA = s2A * (1.0f / 64.0f) - muA * muA;
    accv += (hA - muA) * rsqrtf(vaA + 1e-5f) * gg + eb;
  }
  acc[(size_t)d * 64 + lane] = accv;  // plain store — no atomic
}

// ---------------- GCN degree ----------------
__global__ void deg_init(float* __restrict__ deg) {
  int i = blockIdx.x * blockDim.x + threadIdx.x;
  if (i < N_ATOMS) deg[i] = 1.0f;  // self loop
}
__global__ void deg_count(const int* __restrict__ dst, float* __restrict__ deg) {
  int i = blockIdx.x * blockDim.x + threadIdx.x;
  if (i < E_BOND) atomicAdd(&deg[dst[i]], 1.0f);
}
__global__ void deg_inv(float* __restrict__ deg) {
  int i = blockIdx.x * blockDim.x + threadIdx.x;
  if (i < N_ATOMS) deg[i] = rsqrtf(deg[i]);
}

// ---------------- GCN edges (atomic; only 38 MB of traffic). MUST run after pc1_gather ----------------
__global__ void gcn_edge(const float* __restrict__ xw2, const float* __restrict__ ea,
                         const int* __restrict__ src, const int* __restrict__ dst,
                         const float* __restrict__ W, const float* __restrict__ b,
                         const float* __restrict__ dinv, float* __restrict__ acc) {
  const int lane = threadIdx.x & 63;
  const int wid = (blockIdx.x * blockDim.x + threadIdx.x) >> 6;
  const int nw = (gridDim.x * blockDim.x) >> 6;
  float we[E_DIM];
#pragma unroll
  for (int k = 0; k < E_DIM; k++) we[k] = W[(C_IN + k) * 64 + lane];
  const float bb = b[lane];
  for (int e = wid; e < E_BOND; e += nw) {
    int s = rfl(src[e]);
    int d = rfl(dst[e]);
    float t = xw2[(size_t)s * 64 + lane];
#pragma unroll
    for (int k = 0; k < E_DIM; k++) t += ea[(size_t)e * E_DIM + k] * we[k];
    t = t * (dinv[s] * dinv[d]) + bb;
    atomicAdd(&acc[(size_t)d * 64 + lane], t);
  }
}

// ---------------- atom embed (fused GCN self term) + residue pooling ----------------
__global__ void atom_embed(const float* __restrict__ acc12, const float* __restrict__ xw2,
                           const float* __restrict__ dinv, const float* __restrict__ bgcn,
                           const float* __restrict__ pos, const int* __restrict__ resid,
                           const float* __restrict__ W, const float* __restrict__ b,
                           const float* __restrict__ g, const float* __restrict__ be,
                           float* __restrict__ res_acc, float* __restrict__ res_pacc,
                           float* __restrict__ res_cnt) {
  const int lane = threadIdx.x & 63;
  const int wid = (blockIdx.x * blockDim.x + threadIdx.x) >> 6;
  const int nw = (gridDim.x * blockDim.x) >> 6;
  const float bb = b[lane], gg = g[lane], eb = be[lane], bg = bgcn[lane];
  for (int r = wid; r < N_ATOMS; r += nw) {
    const float di = dinv[r];
    float vin = acc12[(size_t)r * 64 + lane] + xw2[(size_t)r * 64 + lane] * di * di + bg;
    float acc = bb;
#pragma unroll 8
    for (int k = 0; k < 64; k++) {
      float xv = __shfl(vin, k, 64);
      acc += xv * W[k * 64 + lane];
    }
    float h = fmaxf(acc, 0.0f);
    float s1 = h, s2 = h * h;
#pragma unroll
    for (int m = 1; m < 64; m <<= 1) {
      s1 += __shfl_xor(s1, m, 64);
      s2 += __shfl_xor(s2, m, 64);
    }
    float mu = s1 * (1.0f / 64.0f);
    float var = s2 * (1.0f / 64.0f) - mu * mu;
    float v = (h - mu) * rsqrtf(var + 1e-5f) * gg + eb;
    int rr = resid[r];
    atomicAdd(&res_acc[(size_t)rr * 64 + lane], v);
    if (lane < 3) atomicAdd(&res_pacc[rr * 3 + lane], pos[r * 3 + lane]);
    if (lane == 3) atomicAdd(&res_cnt[rr], 1.0f);
  }
}

// ---------------- residue embed + res_pos finalize ----------------
__global__ void res_embed(const float* __restrict__ racc, const float* __restrict__ pacc,
                          const float* __restrict__ cnt, const float* __restrict__ W,
                          const float* __restrict__ b, const float* __restrict__ g,
                          const float* __restrict__ be, float* __restrict__ res_x,
                          float* __restrict__ res_pos) {
  const int lane = threadIdx.x & 63;
  const int wid = (blockIdx.x * blockDim.x + threadIdx.x) >> 6;
  const int nw = (gridDim.x * blockDim.x) >> 6;
  const float bb = b[lane], gg = g[lane], eb = be[lane];
  for (int r = wid; r < N_RES; r += nw) {
    float vin = racc[(size_t)r * 64 + lane];
    float acc = bb;
#pragma unroll 8
    for (int k = 0; k < 64; k++) {
      float xv = __shfl(vin, k, 64);
      acc += xv * W[k * 64 + lane];
    }
    float h = fmaxf(acc, 0.0f);
    float s1 = h, s2 = h * h;
#pragma unroll
    for (int m = 1; m < 64; m <<= 1) {
      s1 += __shfl_xor(s1, m, 64);
      s2 += __shfl_xor(s2, m, 64);
    }
    float mu = s1 * (1.0f / 64.0f);
    float var = s2 * (1.0f / 64.0f) - mu * mu;
    res_x[(size_t)r * 64 + lane] = (h - mu) * rsqrtf(var + 1e-5f) * gg + eb;
    if (lane < 3) res_pos[r * 3 + lane] = pacc[r * 3 + lane] / fmaxf(cnt[r], 1.0f);
  }
}

// ---------------- res_conv precompute: rw = res_x @ W_rc[0:64] + b_rc (128 wide) ----------------
__global__ void rc_pre(const float* __restrict__ rx, const float* __restrict__ W,
                       const float* __restrict__ b, float* __restrict__ rw) {
  const int lane = threadIdx.x & 63;
  const int wid = (blockIdx.x * blockDim.x + threadIdx.x) >> 6;
  const int nw = (gridDim.x * blockDim.x) >> 6;
  for (int r = wid; r < N_RES; r += nw) {
    float vin = rx[(size_t)r * 64 + lane];
    float a0 = b[lane], a1 = b[64 + lane];
#pragma unroll 8
    for (int k = 0; k < 64; k++) {
      float xv = __shfl(vin, k, 64);
      a0 += xv * W[k * 128 + lane];
      a1 += xv * W[k * 128 + 64 + lane];
    }
    rw[(size_t)r * 128 + lane] = a0;
    rw[(size_t)r * 128 + 64 + lane] = a1;
  }
}

// ---------------- res_conv gather: one wave per residue, 128-dim LN, no atomics ----------------
__global__ void rc_gather(const float* __restrict__ rw, const float* __restrict__ rpos,
                          const int* __restrict__ ss, const int* __restrict__ cur,
                          const float* __restrict__ W, const float* __restrict__ g,
                          const float* __restrict__ be, float* __restrict__ out) {
  const int lane = threadIdx.x & 63;
  const int d = (blockIdx.x * blockDim.x + threadIdx.x) >> 6;
  if (d >= N_RES) return;
  float wa[3], wb[3];
#pragma unroll
  for (int i = 0; i < 3; i++) {
    wa[i] = W[(64 + i) * 128 + lane];
    wb[i] = W[(64 + i) * 128 + 64 + lane];
  }
  const float g0 = g[lane], g1 = g[64 + lane], e0c = be[lane], e1c = be[64 + lane];
  const int beg = rfl(d ? cur[d - 1] : 0);
  const int end = rfl(cur[d]);
  const float pd0 = rpos[d * 3 + 0], pd1 = rpos[d * 3 + 1], pd2 = rpos[d * 3 + 2];
  // self loop
  float h0 = fmaxf(rw[(size_t)d * 128 + lane], 0.0f);
  float h1 = fmaxf(rw[(size_t)d * 128 + 64 + lane], 0.0f);
  float s1 = h0 + h1, s2 = h0 * h0 + h1 * h1;
#pragma unroll
  for (int m = 1; m < 64; m <<= 1) {
    s1 += __shfl_xor(s1, m, 64);
    s2 += __shfl_xor(s2, m, 64);
  }
  float mu = s1 * (1.0f / 128.0f);
  float var = s2 * (1.0f / 128.0f) - mu * mu;
  float rs = rsqrtf(var + 1e-5f);
  float a0 = (h0 - mu) * rs * g0 + e0c;
  float a1 = (h1 - mu) * rs * g1 + e1c;
  int j = beg;
  for (; j + 1 < end; j += 2) {
    const int sA = rfl(ss[j]);
    const int sB = rfl(ss[j + 1]);
    const float dA0 = rpos[sA * 3 + 0] - pd0, dA1 = rpos[sA * 3 + 1] - pd1,
                dA2 = rpos[sA * 3 + 2] - pd2;
    const float dB0 = rpos[sB * 3 + 0] - pd0, dB1 = rpos[sB * 3 + 1] - pd1,
                dB2 = rpos[sB * 3 + 2] - pd2;
    float hA0 = fmaxf(rw[(size_t)sA * 128 + lane]      + dA0 * wa[0] + dA1 * wa[1] + dA2 * wa[2], 0.0f);
    float hA1 = fmaxf(rw[(size_t)sA * 128 + 64 + lane] + dA0 * wb[0] + dA1 * wb[1] + dA2 * wb[2], 0.0f);
    float hB0 = fmaxf(rw[(size_t)sB * 128 + lane]      + dB0 * wa[0] + dB1 * wa[1] + dB2 * wa[2], 0.0f);
    float hB1 = fmaxf(rw[(size_t)sB * 128 + 64 + lane] + dB0 * wb[0] + dB1 * wb[1] + dB2 * wb[2], 0.0f);
    float s1A = hA0 + hA1, s2A = hA0 * hA0 + hA1 * hA1;
    float s1B = hB0 + hB1, s2B = hB0 * hB0 + hB1 * hB1;
#pragma unroll
    for (int m = 1; m < 64; m <<= 1) {
      s1A += __shfl_xor(s1A, m, 64);
      s2A += __shfl_xor(s2A, m, 64);
      s1B += __shfl_xor(s1B, m, 64);
      s2B += __shfl_xor(s2B, m, 64);
    }
    const float muA = s1A * (1.0f / 128.0f), muB = s1B * (1.0f / 128.0f);
    const float vaA = s2A * (1.0f / 128.0f) - muA * muA;
    const float vaB = s2B * (1.0f / 128.0f) - muB * muB;
    const float rsA = rsqrtf(vaA + 1e-5f), rsB = rsqrtf(vaB + 1e-5f);
    a0 += (hA0 - muA) * rsA * g0 + e0c + (hB0 - muB) * rsB * g0 + e0c;
    a1 += (hA1 - muA) * rsA * g1 + e1c + (hB1 - muB) * rsB * g1 + e1c;
  }
  if (j < end) {
    const int sA = rfl(ss[j]);
    const float dA0 = rpos[sA * 3 + 0] - pd0, dA1 = rpos[sA * 3 + 1] - pd1,
                dA2 = rpos[sA * 3 + 2] - pd2;
    float hA0 = fmaxf(rw[(size_t)sA * 128 + lane]      + dA0 * wa[0] + dA1 * wa[1] + dA2 * wa[2], 0.0f);
    float hA1 = fmaxf(rw[(size_t)sA * 128 + 64 + lane] + dA0 * wb[0] + dA1 * wb[1] + dA2 * wb[2], 0.0f);
    float s1A = hA0 + hA1, s2A = hA0 * hA0 + hA1 * hA1;
#pragma unroll
    for (int m = 1; m < 64; m <<= 1) {
      s1A += __shfl_xor(s1A, m, 64);
      s2A += __shfl_xor(s2A, m, 64);
    }
    const float muA = s1A * (1.0f / 128.0f);
    const float vaA = s2A * (1.0f / 128.0f) - muA * muA;
    const float rsA = rsqrtf(vaA + 1e-5f);
    a0 += (hA0 - muA) * rsA * g0 + e0c;
    a1 += (hA1 - muA) * rsA * g1 + e1c;
  }
  out[(size_t)d * 128 + lane] = a0;
  out[(size_t)d * 128 + 64 + lane] = a1;
}

// ---------------- global residue MLP: x3 = LN(ReLU(acc @ W_rg + b)) ----------------
__global__ void rg_embed(const float* __restrict__ acc, const float* __restrict__ W,
                         const float* __restrict__ b, const float* __restrict__ g,
                         const float* __restrict__ be, float* __restrict__ x3) {
  const int lane = threadIdx.x & 63;
  const int wid = (blockIdx.x * blockDim.x + threadIdx.x) >> 6;
  const int nw = (gridDim.x * blockDim.x) >> 6;
  for (int r = wid; r < N_RES; r += nw) {
    float i0 = acc[(size_t)r * 128 + lane];
    float i1 = acc[(size_t)r * 128 + 64 + lane];
    float a0 = b[lane], a1 = b[64 + lane];
#pragma unroll 8
    for (int k = 0; k < 64; k++) {
      float x0 = __shfl(i0, k, 64);
      float x1 = __shfl(i1, k, 64);
      a0 += x0 * W[k * 128 + lane] + x1 * W[(k + 64) * 128 + lane];
      a1 += x0 * W[k * 128 + 64 + lane] + x1 * W[(k + 64) * 128 + 64 + lane];
    }
    float h0 = fmaxf(a0, 0.0f), h1 = fmaxf(a1, 0.0f);
    float s1 = h0 + h1, s2 = h0 * h0 + h1 * h1;
#pragma unroll
    for (int m = 1; m < 64; m <<= 1) {
      s1 += __shfl_xor(s1, m, 64);
      s2 += __shfl_xor(s2, m, 64);
    }
    float mu = s1 * (1.0f / 128.0f);
    float var = s2 * (1.0f / 128.0f) - mu * mu;
    float rs = rsqrtf(var + 1e-5f);
    x3[(size_t)r * 128 + lane] = (h0 - mu) * rs * g[lane] + be[lane];
    x3[(size_t)r * 128 + 64 + lane] = (h1 - mu) * rs * g[64 + lane] + be[64 + lane];
  }
}

// ---------------- cosine embedding loss partials ----------------
__global__ void loss_pairs(const float* __restrict__ x3, const int* __restrict__ si,
                           const int* __restrict__ ti, const int* __restrict__ y,
                           float* __restrict__ lacc) {
  const int lane = threadIdx.x & 63;
  const int wid = (blockIdx.x * blockDim.x + threadIdx.x) >> 6;
  const int nw = (gridDim.x * blockDim.x) >> 6;
  float sp = 0.0f, sn = 0.0f, cp = 0.0f, cn = 0.0f;
  for (int p = wid; p < E_CORR; p += nw) {
    int a = rfl(si[p]), bI = rfl(ti[p]), yy = rfl(y[p]);
    float a0 = x3[(size_t)a * 128 + lane], a1 = x3[(size_t)a * 128 + 64 + lane];
    float b0 = x3[(size_t)bI * 128 + lane], b1 = x3[(size_t)bI * 128 + 64 + lane];
    float dot = a0 * b0 + a1 * b1;
    float na = a0 * a0 + a1 * a1;
    float nb = b0 * b0 + b1 * b1;
#pragma unroll
    for (int m = 1; m < 64; m <<= 1) {
      dot += __shfl_xor(dot, m, 64);
      na += __shfl_xor(na, m, 64);
      nb += __shfl_xor(nb, m, 64);
    }
    float cosv = dot / (fmaxf(sqrtf(na), 1e-8f) * fmaxf(sqrtf(nb), 1e-8f));
    if (yy == 1) {
      sp += 1.0f - cosv;
      cp += 1.0f;
    } else {
      sn += fmaxf(cosv, 0.0f);
      cn += 1.0f;
    }
  }
  if (lane == 0) {
    atomicAdd(&lacc[0], sp);
    atomicAdd(&lacc[1], sn);
    atomicAdd(&lacc[2], cp);
    atomicAdd(&lacc[3], cn);
  }
}

__global__ void finalize(const float* __restrict__ lacc, float* __restrict__ out) {
  if (blockIdx.x == 0 && threadIdx.x == 0) {
    float pw = lacc[3] / lacc[2];  // neg_count / pos_count
    out[0] = (lacc[0] * pw + lacc[1]) / (float)E_CORR;
  }
}

// ---------------- launcher ----------------
extern "C" void kernel_launch(void* const* d_in, const int* in_sizes, int n_in,
                              void* d_out, int out_size, void* d_ws, size_t ws_size,
                              hipStream_t stream) {
  const float* x = (const float*)d_in[0];
  const float* pos = (const float*)d_in[1];
  const float* edge_attr = (const float*)d_in[2];
  const int* edge_index = (const int*)d_in[3];       // [2][E_BOND]
  const int* rad_ei = (const int*)d_in[4];           // [2][E_RAD]
  const int* res_rad_ei = (const int*)d_in[5];       // [2][E_RES_RAD]
  const int* resid = (const int*)d_in[6];
  const int* src_idx = (const int*)d_in[7];
  const int* tgt_idx = (const int*)d_in[8];
  const int* y_lab = (const int*)d_in[9];
  const float* w_pc1 = (const float*)d_in[10];
  const float* b_pc1 = (const float*)d_in[11];
  const float* g_pc1 = (const float*)d_in[12];
  const float* be_pc1 = (const float*)d_in[13];
  const float* w_gcn = (const float*)d_in[14];
  const float* b_gcn = (const float*)d_in[15];
  const float* w_ae = (const float*)d_in[16];
  const float* b_ae = (const float*)d_in[17];
  const float* g_ae = (const float*)d_in[18];
  const float* be_ae = (const float*)d_in[19];
  const float* w_re = (const float*)d_in[20];
  const float* b_re = (const float*)d_in[21];
  const float* g_re = (const float*)d_in[22];
  const float* be_re = (const float*)d_in[23];
  const float* w_rc = (const float*)d_in[24];
  const float* b_rc = (const float*)d_in[25];
  const float* g_rc = (const float*)d_in[26];
  const float* be_rc = (const float*)d_in[27];
  const float* w_rg = (const float*)d_in[28];
  const float* b_rg = (const float*)d_in[29];
  const float* g_rg = (const float*)d_in[30];
  const float* be_rg = (const float*)d_in[31];

  float* ws = (float*)d_ws;
  // ---- zeroed region ----
  float* res_acc = ws;                              // 400,000
  float* res_pacc = res_acc + 400000;               // 18,752
  float* res_cnt = res_pacc + 18752;                // 6,272
  float* lacc = res_cnt + 6272;                     // 8
  int* cnt_pc1 = (int*)(lacc + 8);                  // 50,048
  int* cnt_rc = cnt_pc1 + 50048;                    // 6,272
  size_t zero_elems = 400000 + 18752 + 6272 + 8 + 50048 + 6272;
  // ---- non-zeroed region ----
  int* cur_pc1 = cnt_rc + 6272;                     // 50,048
  int* cur_rc = cur_pc1 + 50048;                    // 6,272
  int* ss_pc1 = cur_rc + 6272;                      // 800,000
  int* ss_rc = ss_pc1 + 800000;                     // 400,000
  float* xw1 = (float*)(ss_rc + 400000);            // 3,200,000
  float* xw2 = xw1 + 3200000;                       // 3,200,000
  float* deg = xw2 + 3200000;                       // 50,000
  float* acc12 = deg + 50000;                       // 3,200,000
  float* res_x = acc12 + 3200000;                   // 400,000
  float* res_pos = res_x + 400000;                  // 18,752
  float* rw = res_pos + 18752;                      // 800,000
  float* x3m = acc12;                               // alias: acc12 free after atom_embed
  float* x3 = rw;                                   // alias: rw free after rc_gather

  hipMemsetAsync(d_ws, 0, zero_elems * sizeof(float), stream);

  const int B = 256;
  const int GB = 2048;
  const int GS = 512;

  // node-feature matvecs
  rowmat64<C_IN><<<GB, B, 0, stream>>>(x, w_pc1, xw1, N_ATOMS);
  rowmat64<C_IN><<<GB, B, 0, stream>>>(x, w_gcn, xw2, N_ATOMS);

  // CSR build for atom radius graph (dst = rad_ei + E_RAD)
  hist_kernel<<<(E_RAD + B - 1) / B, B, 0, stream>>>(rad_ei + E_RAD, cnt_pc1, E_RAD);
  ex_scan<<<1, 1024, 0, stream>>>(cnt_pc1, cur_pc1, N_ATOMS);
  scat_kernel<<<(E_RAD + B - 1) / B, B, 0, stream>>>(rad_ei, rad_ei + E_RAD, cur_pc1,
                                                     ss_pc1, E_RAD);
  // PointConv1 gather (plain writes acc12)
  pc1_gather<<<(N_ATOMS * 64 + B - 1) / B, B, 0, stream>>>(xw1, pos, ss_pc1, cur_pc1,
                                                           w_pc1, b_pc1, g_pc1, be_pc1,
                                                           acc12);

  // GCN degree + norm
  deg_init<<<(N_ATOMS + B - 1) / B, B, 0, stream>>>(deg);
  deg_count<<<(E_BOND + B - 1) / B, B, 0, stream>>>(edge_index + E_BOND, deg);
  deg_inv<<<(N_ATOMS + B - 1) / B, B, 0, stream>>>(deg);

  // GCN edges (atomic adds onto acc12, after pc1_gather's init)
  gcn_edge<<<GB, B, 0, stream>>>(xw2, edge_attr, edge_index, edge_index + E_BOND, w_gcn,
                                 b_gcn, deg, acc12);

  // atom embed + residue pooling
  atom_embed<<<GB, B, 0, stream>>>(acc12, xw2, deg, b_gcn, pos, resid, w_ae, b_ae, g_ae,
                                   be_ae, res_acc, res_pacc, res_cnt);

  // residue embed
  res_embed<<<GS, B, 0, stream>>>(res_acc, res_pacc, res_cnt, w_re, b_re, g_re, be_re,
                                  res_x, res_pos);

  // CSR build for residue radius graph
  hist_kernel<<<(E_RES_RAD + B - 1) / B, B, 0, stream>>>(res_rad_ei + E_RES_RAD, cnt_rc,
                                                         E_RES_RAD);
  ex_scan<<<1, 1024, 0, stream>>>(cnt_rc, cur_rc, N_RES);
  scat_kernel<<<(E_RES_RAD + B - 1) / B, B, 0, stream>>>(res_rad_ei,
                                                         res_rad_ei + E_RES_RAD, cur_rc,
                                                         ss_rc, E_RES_RAD);

  // residue PointConv
  rc_pre<<<GS, B, 0, stream>>>(res_x, w_rc, b_rc, rw);
  rc_gather<<<(N_RES * 64 + B - 1) / B, B, 0, stream>>>(rw, res_pos, ss_rc, cur_rc, w_rc,
                                                        g_rc, be_rc, x3m);
  rg_embed<<<GS, B, 0, stream>>>(x3m, w_rg, b_rg, g_rg, be_rg, x3);

  // loss
  loss_pairs<<<GS, B, 0, stream>>>(x3, src_idx, tgt_idx, y_lab, lacc);
  finalize<<<1, 64, 0, stream>>>(lacc, (float*)d_out);
}

// Round 8
// 747.430 us; speedup vs baseline: 1.0579x; 1.0579x over previous
//
#include <hip/hip_runtime.h>
#include <math.h>

#define N_ATOMS 50000
#define N_RES 6250
#define C_IN 30
#define E_DIM 12
#define E_BOND 150000
#define E_RAD 800000
#define E_RES_RAD 400000
#define E_CORR 20000

__device__ __forceinline__ int rfl(int v) { return __builtin_amdgcn_readfirstlane(v); }

// ---------------- generic row matvec: out[r][0:64] = X[r][0:K] @ W[K][64] ----------------
template <int K>
__global__ void rowmat64(const float* __restrict__ X, const float* __restrict__ W,
                         float* __restrict__ out, int nrows) {
  const int lane = threadIdx.x & 63;
  const int wid = (blockIdx.x * blockDim.x + threadIdx.x) >> 6;
  const int nw = (gridDim.x * blockDim.x) >> 6;
  float wcol[K];
#pragma unroll
  for (int k = 0; k < K; k++) wcol[k] = W[k * 64 + lane];
  for (int r = wid; r < nrows; r += nw) {
    float acc = 0.0f;
#pragma unroll
    for (int k = 0; k < K; k++) acc += X[(size_t)r * K + k] * wcol[k];
    out[(size_t)r * 64 + lane] = acc;
  }
}

// ---------------- merged histogram for both graphs ----------------
__global__ void hist2(const int* __restrict__ d0, int* __restrict__ c0, int n0,
                      const int* __restrict__ d1, int* __restrict__ c1, int n1) {
  int i = blockIdx.x * blockDim.x + threadIdx.x;
  if (i < n0) {
    atomicAdd(&c0[d0[i]], 1);
  } else {
    int k = i - n0;
    if (k < n1) atomicAdd(&c1[d1[k]], 1);
  }
}

// ---------------- dual exclusive scan: block 0 -> (c0,u0,n0), block 1 -> (c1,u1,n1) ----------------
// 4 items/thread: 4096 items per chunk-iteration.
__global__ void dual_scan(const int* __restrict__ c0, int* __restrict__ u0, int n0,
                          const int* __restrict__ c1, int* __restrict__ u1, int n1) {
  const int* cnt = blockIdx.x ? c1 : c0;
  int* cur = blockIdx.x ? u1 : u0;
  const int n = blockIdx.x ? n1 : n0;
  __shared__ int wsums[16];
  __shared__ int carry_s;
  const int tid = threadIdx.x;
  const int lane = tid & 63;
  const int w = tid >> 6;
  if (tid == 0) carry_s = 0;
  __syncthreads();
  for (int base = 0; base < n; base += 4096) {
    const int i0 = base + tid * 4;
    int v0 = (i0 + 0 < n) ? cnt[i0 + 0] : 0;
    int v1 = (i0 + 1 < n) ? cnt[i0 + 1] : 0;
    int v2 = (i0 + 2 < n) ? cnt[i0 + 2] : 0;
    int v3 = (i0 + 3 < n) ? cnt[i0 + 3] : 0;
    const int t0 = v0, t1 = t0 + v1, t2 = t1 + v2, t3 = t2 + v3;  // thread-local inclusive
    int s = t3;
#pragma unroll
    for (int m = 1; m < 64; m <<= 1) {
      int t = __shfl_up(s, m, 64);
      if (lane >= m) s += t;
    }
    if (lane == 63) wsums[w] = s;
    __syncthreads();
    if (w == 0) {
      int x = (lane < 16) ? wsums[lane] : 0;
#pragma unroll
      for (int m = 1; m < 16; m <<= 1) {
        int t = __shfl_up(x, m, 64);
        if (lane >= m) x += t;
      }
      if (lane < 16) wsums[lane] = x;
    }
    __syncthreads();
    const int woff = (w > 0) ? wsums[w - 1] : 0;
    const int off = carry_s + woff + (s - t3);  // exclusive prefix for item i0
    if (i0 + 0 < n) cur[i0 + 0] = off;
    if (i0 + 1 < n) cur[i0 + 1] = off + t0;
    if (i0 + 2 < n) cur[i0 + 2] = off + t1;
    if (i0 + 3 < n) cur[i0 + 3] = off + t2;
    __syncthreads();
    if (tid == 1023) carry_s += wsums[15];
    __syncthreads();
  }
}

// ---------------- merged scatter for both graphs ----------------
// cur[d] walks exclusive->inclusive; afterwards start(d)=cur[d-1], end(d)=cur[d]
__global__ void scat2(const int* __restrict__ s0, const int* __restrict__ d0,
                      int* __restrict__ u0, int* __restrict__ o0, int n0,
                      const int* __restrict__ s1, const int* __restrict__ d1,
                      int* __restrict__ u1, int* __restrict__ o1, int n1) {
  int i = blockIdx.x * blockDim.x + threadIdx.x;
  if (i < n0) {
    int p = atomicAdd(&u0[d0[i]], 1);
    o0[p] = s0[i];
  } else {
    int k = i - n0;
    if (k < n1) {
      int p = atomicAdd(&u1[d1[k]], 1);
      o1[p] = s1[k];
    }
  }
}

// ---------------- PointConv1 gather: one wave per atom, ILP-4, no atomics ----------------
__global__ void pc1_gather(const float* __restrict__ xw1, const float* __restrict__ pos,
                           const int* __restrict__ ss, const int* __restrict__ cur,
                           const float* __restrict__ W, const float* __restrict__ b,
                           const float* __restrict__ g, const float* __restrict__ be,
                           float* __restrict__ acc) {
  const int lane = threadIdx.x & 63;
  const int d = (blockIdx.x * blockDim.x + threadIdx.x) >> 6;
  if (d >= N_ATOMS) return;
  const float w0 = W[(C_IN + 0) * 64 + lane];
  const float w1 = W[(C_IN + 1) * 64 + lane];
  const float w2 = W[(C_IN + 2) * 64 + lane];
  const float bb = b[lane], gg = g[lane], eb = be[lane];
  const int beg = rfl(d ? cur[d - 1] : 0);
  const int end = rfl(cur[d]);
  const float pd0 = pos[d * 3 + 0], pd1 = pos[d * 3 + 1], pd2 = pos[d * 3 + 2];
  // self loop: dp = 0
  float h = fmaxf(xw1[(size_t)d * 64 + lane] + bb, 0.0f);
  float p1 = h, p2 = h * h;
#pragma unroll
  for (int m = 1; m < 64; m <<= 1) {
    p1 += __shfl_xor(p1, m, 64);
    p2 += __shfl_xor(p2, m, 64);
  }
  float mu = p1 * (1.0f / 64.0f);
  float var = p2 * (1.0f / 64.0f) - mu * mu;
  float accv = (h - mu) * rsqrtf(var + 1e-5f) * gg + eb;
  int j = beg;
  // ---- quad ILP ----
  for (; j + 3 < end; j += 4) {
    const int sA = rfl(ss[j]);
    const int sB = rfl(ss[j + 1]);
    const int sC = rfl(ss[j + 2]);
    const int sD = rfl(ss[j + 3]);
    const float dA0 = pos[sA * 3 + 0] - pd0, dA1 = pos[sA * 3 + 1] - pd1, dA2 = pos[sA * 3 + 2] - pd2;
    const float dB0 = pos[sB * 3 + 0] - pd0, dB1 = pos[sB * 3 + 1] - pd1, dB2 = pos[sB * 3 + 2] - pd2;
    const float dC0 = pos[sC * 3 + 0] - pd0, dC1 = pos[sC * 3 + 1] - pd1, dC2 = pos[sC * 3 + 2] - pd2;
    const float dD0 = pos[sD * 3 + 0] - pd0, dD1 = pos[sD * 3 + 1] - pd1, dD2 = pos[sD * 3 + 2] - pd2;
    float hA = fmaxf(xw1[(size_t)sA * 64 + lane] + bb + dA0 * w0 + dA1 * w1 + dA2 * w2, 0.0f);
    float hB = fmaxf(xw1[(size_t)sB * 64 + lane] + bb + dB0 * w0 + dB1 * w1 + dB2 * w2, 0.0f);
    float hC = fmaxf(xw1[(size_t)sC * 64 + lane] + bb + dC0 * w0 + dC1 * w1 + dC2 * w2, 0.0f);
    float hD = fmaxf(xw1[(size_t)sD * 64 + lane] + bb + dD0 * w0 + dD1 * w1 + dD2 * w2, 0.0f);
    float p1A = hA, p2A = hA * hA, p1B = hB, p2B = hB * hB;
    float p1C = hC, p2C = hC * hC, p1D = hD, p2D = hD * hD;
#pragma unroll
    for (int m = 1; m < 64; m <<= 1) {
      p1A += __shfl_xor(p1A, m, 64);
      p2A += __shfl_xor(p2A, m, 64);
      p1B += __shfl_xor(p1B, m, 64);
      p2B += __shfl_xor(p2B, m, 64);
      p1C += __shfl_xor(p1C, m, 64);
      p2C += __shfl_xor(p2C, m, 64);
      p1D += __shfl_xor(p1D, m, 64);
      p2D += __shfl_xor(p2D, m, 64);
    }
    const float muA = p1A * (1.0f / 64.0f), muB = p1B * (1.0f / 64.0f);
    const float muC = p1C * (1.0f / 64.0f), muD = p1D * (1.0f / 64.0f);
    const float vaA = p2A * (1.0f / 64.0f) - muA * muA;
    const float vaB = p2B * (1.0f / 64.0f) - muB * muB;
    const float vaC = p2C * (1.0f / 64.0f) - muC * muC;
    const float vaD = p2D * (1.0f / 64.0f) - muD * muD;
    accv += (hA - muA) * rsqrtf(vaA + 1e-5f) * gg + eb;
    accv += (hB - muB) * rsqrtf(vaB + 1e-5f) * gg + eb;
    accv += (hC - muC) * rsqrtf(vaC + 1e-5f) * gg + eb;
    accv += (hD - muD) * rsqrtf(vaD + 1e-5f) * gg + eb;
  }
  // ---- pair ----
  for (; j + 1 < end; j += 2) {
    const int sA = rfl(ss[j]);
    const int sB = rfl(ss[j + 1]);
    const float dA0 = pos[sA * 3 + 0] - pd0, dA1 = pos[sA * 3 + 1] - pd1, dA2 = pos[sA * 3 + 2] - pd2;
    const float dB0 = pos[sB * 3 + 0] - pd0, dB1 = pos[sB * 3 + 1] - pd1, dB2 = pos[sB * 3 + 2] - pd2;
    float hA = fmaxf(xw1[(size_t)sA * 64 + lane] + bb + dA0 * w0 + dA1 * w1 + dA2 * w2, 0.0f);
    float hB = fmaxf(xw1[(size_t)sB * 64 + lane] + bb + dB0 * w0 + dB1 * w1 + dB2 * w2, 0.0f);
    float p1A = hA, p2A = hA * hA, p1B = hB, p2B = hB * hB;
#pragma unroll
    for (int m = 1; m < 64; m <<= 1) {
      p1A += __shfl_xor(p1A, m, 64);
      p2A += __shfl_xor(p2A, m, 64);
      p1B += __shfl_xor(p1B, m, 64);
      p2B += __shfl_xor(p2B, m, 64);
    }
    const float muA = p1A * (1.0f / 64.0f), muB = p1B * (1.0f / 64.0f);
    const float vaA = p2A * (1.0f / 64.0f) - muA * muA;
    const float vaB = p2B * (1.0f / 64.0f) - muB * muB;
    accv += (hA - muA) * rsqrtf(vaA + 1e-5f) * gg + eb;
    accv += (hB - muB) * rsqrtf(vaB + 1e-5f) * gg + eb;
  }
  if (j < end) {
    const int sA = rfl(ss[j]);
    const float dA0 = pos[sA * 3 + 0] - pd0, dA1 = pos[sA * 3 + 1] - pd1, dA2 = pos[sA * 3 + 2] - pd2;
    float hA = fmaxf(xw1[(size_t)sA * 64 + lane] + bb + dA0 * w0 + dA1 * w1 + dA2 * w2, 0.0f);
    float p1A = hA, p2A = hA * hA;
#pragma unroll
    for (int m = 1; m < 64; m <<= 1) {
      p1A += __shfl_xor(p1A, m, 64);
      p2A += __shfl_xor(p2A, m, 64);
    }
    const float muA = p1A * (1.0f / 64.0f);
    const float vaA = p2A * (1.0f / 64.0f) - muA * muA;
    accv += (hA - muA) * rsqrtf(vaA + 1e-5f) * gg + eb;
  }
  acc[(size_t)d * 64 + lane] = accv;  // plain store — no atomic
}

// ---------------- GCN degree ----------------
__global__ void deg_init(float* __restrict__ deg) {
  int i = blockIdx.x * blockDim.x + threadIdx.x;
  if (i < N_ATOMS) deg[i] = 1.0f;  // self loop
}
__global__ void deg_count(const int* __restrict__ dst, float* __restrict__ deg) {
  int i = blockIdx.x * blockDim.x + threadIdx.x;
  if (i < E_BOND) atomicAdd(&deg[dst[i]], 1.0f);
}
__global__ void deg_inv(float* __restrict__ deg) {
  int i = blockIdx.x * blockDim.x + threadIdx.x;
  if (i < N_ATOMS) deg[i] = rsqrtf(deg[i]);
}

// ---------------- GCN edges (atomic; ~38 MB traffic). MUST run after pc1_gather ----------------
__global__ void gcn_edge(const float* __restrict__ xw2, const float* __restrict__ ea,
                         const int* __restrict__ src, const int* __restrict__ dst,
                         const float* __restrict__ W, const float* __restrict__ b,
                         const float* __restrict__ dinv, float* __restrict__ acc) {
  const int lane = threadIdx.x & 63;
  const int wid = (blockIdx.x * blockDim.x + threadIdx.x) >> 6;
  const int nw = (gridDim.x * blockDim.x) >> 6;
  float we[E_DIM];
#pragma unroll
  for (int k = 0; k < E_DIM; k++) we[k] = W[(C_IN + k) * 64 + lane];
  const float bb = b[lane];
  for (int e = wid; e < E_BOND; e += nw) {
    int s = rfl(src[e]);
    int d = rfl(dst[e]);
    float t = xw2[(size_t)s * 64 + lane];
#pragma unroll
    for (int k = 0; k < E_DIM; k++) t += ea[(size_t)e * E_DIM + k] * we[k];
    t = t * (dinv[s] * dinv[d]) + bb;
    atomicAdd(&acc[(size_t)d * 64 + lane], t);
  }
}

// ---------------- atom embed (fused GCN self term) + residue pooling ----------------
__global__ void atom_embed(const float* __restrict__ acc12, const float* __restrict__ xw2,
                           const float* __restrict__ dinv, const float* __restrict__ bgcn,
                           const float* __restrict__ pos, const int* __restrict__ resid,
                           const float* __restrict__ W, const float* __restrict__ b,
                           const float* __restrict__ g, const float* __restrict__ be,
                           float* __restrict__ res_acc, float* __restrict__ res_pacc,
                           float* __restrict__ res_cnt) {
  const int lane = threadIdx.x & 63;
  const int wid = (blockIdx.x * blockDim.x + threadIdx.x) >> 6;
  const int nw = (gridDim.x * blockDim.x) >> 6;
  const float bb = b[lane], gg = g[lane], eb = be[lane], bg = bgcn[lane];
  for (int r = wid; r < N_ATOMS; r += nw) {
    const float di = dinv[r];
    float vin = acc12[(size_t)r * 64 + lane] + xw2[(size_t)r * 64 + lane] * di * di + bg;
    float acc = bb;
#pragma unroll 8
    for (int k = 0; k < 64; k++) {
      float xv = __shfl(vin, k, 64);
      acc += xv * W[k * 64 + lane];
    }
    float h = fmaxf(acc, 0.0f);
    float s1 = h, s2 = h * h;
#pragma unroll
    for (int m = 1; m < 64; m <<= 1) {
      s1 += __shfl_xor(s1, m, 64);
      s2 += __shfl_xor(s2, m, 64);
    }
    float mu = s1 * (1.0f / 64.0f);
    float var = s2 * (1.0f / 64.0f) - mu * mu;
    float v = (h - mu) * rsqrtf(var + 1e-5f) * gg + eb;
    int rr = resid[r];
    atomicAdd(&res_acc[(size_t)rr * 64 + lane], v);
    if (lane < 3) atomicAdd(&res_pacc[rr * 3 + lane], pos[r * 3 + lane]);
    if (lane == 3) atomicAdd(&res_cnt[rr], 1.0f);
  }
}

// ---------------- residue embed + res_pos finalize ----------------
__global__ void res_embed(const float* __restrict__ racc, const float* __restrict__ pacc,
                          const float* __restrict__ cnt, const float* __restrict__ W,
                          const float* __restrict__ b, const float* __restrict__ g,
                          const float* __restrict__ be, float* __restrict__ res_x,
                          float* __restrict__ res_pos) {
  const int lane = threadIdx.x & 63;
  const int wid = (blockIdx.x * blockDim.x + threadIdx.x) >> 6;
  const int nw = (gridDim.x * blockDim.x) >> 6;
  const float bb = b[lane], gg = g[lane], eb = be[lane];
  for (int r = wid; r < N_RES; r += nw) {
    float vin = racc[(size_t)r * 64 + lane];
    float acc = bb;
#pragma unroll 8
    for (int k = 0; k < 64; k++) {
      float xv = __shfl(vin, k, 64);
      acc += xv * W[k * 64 + lane];
    }
    float h = fmaxf(acc, 0.0f);
    float s1 = h, s2 = h * h;
#pragma unroll
    for (int m = 1; m < 64; m <<= 1) {
      s1 += __shfl_xor(s1, m, 64);
      s2 += __shfl_xor(s2, m, 64);
    }
    float mu = s1 * (1.0f / 64.0f);
    float var = s2 * (1.0f / 64.0f) - mu * mu;
    res_x[(size_t)r * 64 + lane] = (h - mu) * rsqrtf(var + 1e-5f) * gg + eb;
    if (lane < 3) res_pos[r * 3 + lane] = pacc[r * 3 + lane] / fmaxf(cnt[r], 1.0f);
  }
}

// ---------------- res_conv precompute: rw = res_x @ W_rc[0:64] + b_rc (128 wide) ----------------
__global__ void rc_pre(const float* __restrict__ rx, const float* __restrict__ W,
                       const float* __restrict__ b, float* __restrict__ rw) {
  const int lane = threadIdx.x & 63;
  const int wid = (blockIdx.x * blockDim.x + threadIdx.x) >> 6;
  const int nw = (gridDim.x * blockDim.x) >> 6;
  for (int r = wid; r < N_RES; r += nw) {
    float vin = rx[(size_t)r * 64 + lane];
    float a0 = b[lane], a1 = b[64 + lane];
#pragma unroll 8
    for (int k = 0; k < 64; k++) {
      float xv = __shfl(vin, k, 64);
      a0 += xv * W[k * 128 + lane];
      a1 += xv * W[k * 128 + 64 + lane];
    }
    rw[(size_t)r * 128 + lane] = a0;
    rw[(size_t)r * 128 + 64 + lane] = a1;
  }
}

// ---------------- res_conv gather: 4 waves per residue (parallelism fix), partial atomics ----------------
#define RPW 4
__global__ void rc_gather(const float* __restrict__ rw, const float* __restrict__ rpos,
                          const int* __restrict__ ss, const int* __restrict__ cur,
                          const float* __restrict__ W, const float* __restrict__ g,
                          const float* __restrict__ be, float* __restrict__ out) {
  const int lane = threadIdx.x & 63;
  const int gw = (blockIdx.x * blockDim.x + threadIdx.x) >> 6;
  const int d = gw >> 2;   // residue
  const int q = gw & 3;    // part
  if (d >= N_RES) return;
  float wa[3], wb[3];
#pragma unroll
  for (int i = 0; i < 3; i++) {
    wa[i] = W[(64 + i) * 128 + lane];
    wb[i] = W[(64 + i) * 128 + 64 + lane];
  }
  const float g0 = g[lane], g1 = g[64 + lane], e0c = be[lane], e1c = be[64 + lane];
  const int beg = rfl(d ? cur[d - 1] : 0);
  const int end = rfl(cur[d]);
  const int len = end - beg;
  const int chunk = (len + RPW - 1) >> 2;
  int j = beg + q * chunk;
  const int je = min(j + chunk, end);
  const float pd0 = rpos[d * 3 + 0], pd1 = rpos[d * 3 + 1], pd2 = rpos[d * 3 + 2];
  float a0 = 0.0f, a1 = 0.0f;
  if (q == 0) {
    // self loop
    float h0 = fmaxf(rw[(size_t)d * 128 + lane], 0.0f);
    float h1 = fmaxf(rw[(size_t)d * 128 + 64 + lane], 0.0f);
    float p1 = h0 + h1, p2 = h0 * h0 + h1 * h1;
#pragma unroll
    for (int m = 1; m < 64; m <<= 1) {
      p1 += __shfl_xor(p1, m, 64);
      p2 += __shfl_xor(p2, m, 64);
    }
    float mu = p1 * (1.0f / 128.0f);
    float var = p2 * (1.0f / 128.0f) - mu * mu;
    float rs = rsqrtf(var + 1e-5f);
    a0 = (h0 - mu) * rs * g0 + e0c;
    a1 = (h1 - mu) * rs * g1 + e1c;
  }
  for (; j + 1 < je; j += 2) {
    const int sA = rfl(ss[j]);
    const int sB = rfl(ss[j + 1]);
    const float dA0 = rpos[sA * 3 + 0] - pd0, dA1 = rpos[sA * 3 + 1] - pd1, dA2 = rpos[sA * 3 + 2] - pd2;
    const float dB0 = rpos[sB * 3 + 0] - pd0, dB1 = rpos[sB * 3 + 1] - pd1, dB2 = rpos[sB * 3 + 2] - pd2;
    float hA0 = fmaxf(rw[(size_t)sA * 128 + lane]      + dA0 * wa[0] + dA1 * wa[1] + dA2 * wa[2], 0.0f);
    float hA1 = fmaxf(rw[(size_t)sA * 128 + 64 + lane] + dA0 * wb[0] + dA1 * wb[1] + dA2 * wb[2], 0.0f);
    float hB0 = fmaxf(rw[(size_t)sB * 128 + lane]      + dB0 * wa[0] + dB1 * wa[1] + dB2 * wa[2], 0.0f);
    float hB1 = fmaxf(rw[(size_t)sB * 128 + 64 + lane] + dB0 * wb[0] + dB1 * wb[1] + dB2 * wb[2], 0.0f);
    float p1A = hA0 + hA1, p2A = hA0 * hA0 + hA1 * hA1;
    float p1B = hB0 + hB1, p2B = hB0 * hB0 + hB1 * hB1;
#pragma unroll
    for (int m = 1; m < 64; m <<= 1) {
      p1A += __shfl_xor(p1A, m, 64);
      p2A += __shfl_xor(p2A, m, 64);
      p1B += __shfl_xor(p1B, m, 64);
      p2B += __shfl_xor(p2B, m, 64);
    }
    const float muA = p1A * (1.0f / 128.0f), muB = p1B * (1.0f / 128.0f);
    const float vaA = p2A * (1.0f / 128.0f) - muA * muA;
    const float vaB = p2B * (1.0f / 128.0f) - muB * muB;
    const float rsA = rsqrtf(vaA + 1e-5f), rsB = rsqrtf(vaB + 1e-5f);
    a0 += (hA0 - muA) * rsA * g0 + e0c + (hB0 - muB) * rsB * g0 + e0c;
    a1 += (hA1 - muA) * rsA * g1 + e1c + (hB1 - muB) * rsB * g1 + e1c;
  }
  if (j < je) {
    const int sA = rfl(ss[j]);
    const float dA0 = rpos[sA * 3 + 0] - pd0, dA1 = rpos[sA * 3 + 1] - pd1, dA2 = rpos[sA * 3 + 2] - pd2;
    float hA0 = fmaxf(rw[(size_t)sA * 128 + lane]      + dA0 * wa[0] + dA1 * wa[1] + dA2 * wa[2], 0.0f);
    float hA1 = fmaxf(rw[(size_t)sA * 128 + 64 + lane] + dA0 * wb[0] + dA1 * wb[1] + dA2 * wb[2], 0.0f);
    float p1A = hA0 + hA1, p2A = hA0 * hA0 + hA1 * hA1;
#pragma unroll
    for (int m = 1; m < 64; m <<= 1) {
      p1A += __shfl_xor(p1A, m, 64);
      p2A += __shfl_xor(p2A, m, 64);
    }
    const float muA = p1A * (1.0f / 128.0f);
    const float vaA = p2A * (1.0f / 128.0f) - muA * muA;
    const float rsA = rsqrtf(vaA + 1e-5f);
    a0 += (hA0 - muA) * rsA * g0 + e0c;
    a1 += (hA1 - muA) * rsA * g1 + e1c;
  }
  atomicAdd(&out[(size_t)d * 128 + lane], a0);
  atomicAdd(&out[(size_t)d * 128 + 64 + lane], a1);
}

// ---------------- global residue MLP: x3 = LN(ReLU(acc @ W_rg + b)) ----------------
__global__ void rg_embed(const float* __restrict__ acc, const float* __restrict__ W,
                         const float* __restrict__ b, const float* __restrict__ g,
                         const float* __restrict__ be, float* __restrict__ x3) {
  const int lane = threadIdx.x & 63;
  const int wid = (blockIdx.x * blockDim.x + threadIdx.x) >> 6;
  const int nw = (gridDim.x * blockDim.x) >> 6;
  for (int r = wid; r < N_RES; r += nw) {
    float i0 = acc[(size_t)r * 128 + lane];
    float i1 = acc[(size_t)r * 128 + 64 + lane];
    float a0 = b[lane], a1 = b[64 + lane];
#pragma unroll 8
    for (int k = 0; k < 64; k++) {
      float x0 = __shfl(i0, k, 64);
      float x1 = __shfl(i1, k, 64);
      a0 += x0 * W[k * 128 + lane] + x1 * W[(k + 64) * 128 + lane];
      a1 += x0 * W[k * 128 + 64 + lane] + x1 * W[(k + 64) * 128 + 64 + lane];
    }
    float h0 = fmaxf(a0, 0.0f), h1 = fmaxf(a1, 0.0f);
    float s1 = h0 + h1, s2 = h0 * h0 + h1 * h1;
#pragma unroll
    for (int m = 1; m < 64; m <<= 1) {
      s1 += __shfl_xor(s1, m, 64);
      s2 += __shfl_xor(s2, m, 64);
    }
    float mu = s1 * (1.0f / 128.0f);
    float var = s2 * (1.0f / 128.0f) - mu * mu;
    float rs = rsqrtf(var + 1e-5f);
    x3[(size_t)r * 128 + lane] = (h0 - mu) * rs * g[lane] + be[lane];
    x3[(size_t)r * 128 + 64 + lane] = (h1 - mu) * rs * g[64 + lane] + be[64 + lane];
  }
}

// ---------------- cosine embedding loss partials ----------------
__global__ void loss_pairs(const float* __restrict__ x3, const int* __restrict__ si,
                           const int* __restrict__ ti, const int* __restrict__ y,
                           float* __restrict__ lacc) {
  const int lane = threadIdx.x & 63;
  const int wid = (blockIdx.x * blockDim.x + threadIdx.x) >> 6;
  const int nw = (gridDim.x * blockDim.x) >> 6;
  float sp = 0.0f, sn = 0.0f, cp = 0.0f, cn = 0.0f;
  for (int p = wid; p < E_CORR; p += nw) {
    int a = rfl(si[p]), bI = rfl(ti[p]), yy = rfl(y[p]);
    float a0 = x3[(size_t)a * 128 + lane], a1 = x3[(size_t)a * 128 + 64 + lane];
    float b0 = x3[(size_t)bI * 128 + lane], b1 = x3[(size_t)bI * 128 + 64 + lane];
    float dot = a0 * b0 + a1 * b1;
    float na = a0 * a0 + a1 * a1;
    float nb = b0 * b0 + b1 * b1;
#pragma unroll
    for (int m = 1; m < 64; m <<= 1) {
      dot += __shfl_xor(dot, m, 64);
      na += __shfl_xor(na, m, 64);
      nb += __shfl_xor(nb, m, 64);
    }
    float cosv = dot / (fmaxf(sqrtf(na), 1e-8f) * fmaxf(sqrtf(nb), 1e-8f));
    if (yy == 1) {
      sp += 1.0f - cosv;
      cp += 1.0f;
    } else {
      sn += fmaxf(cosv, 0.0f);
      cn += 1.0f;
    }
  }
  if (lane == 0) {
    atomicAdd(&lacc[0], sp);
    atomicAdd(&lacc[1], sn);
    atomicAdd(&lacc[2], cp);
    atomicAdd(&lacc[3], cn);
  }
}

__global__ void finalize(const float* __restrict__ lacc, float* __restrict__ out) {
  if (blockIdx.x == 0 && threadIdx.x == 0) {
    float pw = lacc[3] / lacc[2];  // neg_count / pos_count
    out[0] = (lacc[0] * pw + lacc[1]) / (float)E_CORR;
  }
}

// ---------------- launcher ----------------
extern "C" void kernel_launch(void* const* d_in, const int* in_sizes, int n_in,
                              void* d_out, int out_size, void* d_ws, size_t ws_size,
                              hipStream_t stream) {
  const float* x = (const float*)d_in[0];
  const float* pos = (const float*)d_in[1];
  const float* edge_attr = (const float*)d_in[2];
  const int* edge_index = (const int*)d_in[3];       // [2][E_BOND]
  const int* rad_ei = (const int*)d_in[4];           // [2][E_RAD]
  const int* res_rad_ei = (const int*)d_in[5];       // [2][E_RES_RAD]
  const int* resid = (const int*)d_in[6];
  const int* src_idx = (const int*)d_in[7];
  const int* tgt_idx = (const int*)d_in[8];
  const int* y_lab = (const int*)d_in[9];
  const float* w_pc1 = (const float*)d_in[10];
  const float* b_pc1 = (const float*)d_in[11];
  const float* g_pc1 = (const float*)d_in[12];
  const float* be_pc1 = (const float*)d_in[13];
  const float* w_gcn = (const float*)d_in[14];
  const float* b_gcn = (const float*)d_in[15];
  const float* w_ae = (const float*)d_in[16];
  const float* b_ae = (const float*)d_in[17];
  const float* g_ae = (const float*)d_in[18];
  const float* be_ae = (const float*)d_in[19];
  const float* w_re = (const float*)d_in[20];
  const float* b_re = (const float*)d_in[21];
  const float* g_re = (const float*)d_in[22];
  const float* be_re = (const float*)d_in[23];
  const float* w_rc = (const float*)d_in[24];
  const float* b_rc = (const float*)d_in[25];
  const float* g_rc = (const float*)d_in[26];
  const float* be_rc = (const float*)d_in[27];
  const float* w_rg = (const float*)d_in[28];
  const float* b_rg = (const float*)d_in[29];
  const float* g_rg = (const float*)d_in[30];
  const float* be_rg = (const float*)d_in[31];

  float* ws = (float*)d_ws;
  // ---- zeroed region ----
  float* res_acc = ws;                              // 400,000
  float* res_pacc = res_acc + 400000;               // 18,752
  float* res_cnt = res_pacc + 18752;                // 6,272
  float* lacc = res_cnt + 6272;                     // 8
  int* cnt_pc1 = (int*)(lacc + 8);                  // 50,048
  int* cnt_rc = cnt_pc1 + 50048;                    // 6,272
  float* x3acc = (float*)(cnt_rc + 6272);           // 800,000 (zeroed: rc_gather atomicAdds)
  size_t zero_elems = 400000 + 18752 + 6272 + 8 + 50048 + 6272 + 800000;
  // ---- non-zeroed region ----
  int* cur_pc1 = (int*)(x3acc + 800000);            // 50,048
  int* cur_rc = cur_pc1 + 50048;                    // 6,272
  int* ss_pc1 = cur_rc + 6272;                      // 800,000
  int* ss_rc = ss_pc1 + 800000;                     // 400,000
  float* xw1 = (float*)(ss_rc + 400000);            // 3,200,000
  float* xw2 = xw1 + 3200000;                       // 3,200,000
  float* deg = xw2 + 3200000;                       // 50,000
  float* acc12 = deg + 50000;                       // 3,200,000
  float* res_x = acc12 + 3200000;                   // 400,000
  float* res_pos = res_x + 400000;                  // 18,752
  float* rw = res_pos + 18752;                      // 800,000
  float* x3 = rw;                                   // alias: rw free after rc_gather (rg reads x3acc)

  hipMemsetAsync(d_ws, 0, zero_elems * sizeof(float), stream);

  const int B = 256;
  const int GB = 2048;
  const int GS = 512;

  // node-feature matvecs
  rowmat64<C_IN><<<GB, B, 0, stream>>>(x, w_pc1, xw1, N_ATOMS);
  rowmat64<C_IN><<<GB, B, 0, stream>>>(x, w_gcn, xw2, N_ATOMS);

  // merged CSR build for both radius graphs
  hist2<<<(E_RAD + E_RES_RAD + B - 1) / B, B, 0, stream>>>(
      rad_ei + E_RAD, cnt_pc1, E_RAD, res_rad_ei + E_RES_RAD, cnt_rc, E_RES_RAD);
  dual_scan<<<2, 1024, 0, stream>>>(cnt_pc1, cur_pc1, N_ATOMS, cnt_rc, cur_rc, N_RES);
  scat2<<<(E_RAD + E_RES_RAD + B - 1) / B, B, 0, stream>>>(
      rad_ei, rad_ei + E_RAD, cur_pc1, ss_pc1, E_RAD,
      res_rad_ei, res_rad_ei + E_RES_RAD, cur_rc, ss_rc, E_RES_RAD);

  // PointConv1 gather (plain writes acc12)
  pc1_gather<<<(N_ATOMS * 64 + B - 1) / B, B, 0, stream>>>(xw1, pos, ss_pc1, cur_pc1,
                                                           w_pc1, b_pc1, g_pc1, be_pc1,
                                                           acc12);

  // GCN degree + norm
  deg_init<<<(N_ATOMS + B - 1) / B, B, 0, stream>>>(deg);
  deg_count<<<(E_BOND + B - 1) / B, B, 0, stream>>>(edge_index + E_BOND, deg);
  deg_inv<<<(N_ATOMS + B - 1) / B, B, 0, stream>>>(deg);

  // GCN edges (atomic adds onto acc12, after pc1_gather's init)
  gcn_edge<<<GB, B, 0, stream>>>(xw2, edge_attr, edge_index, edge_index + E_BOND, w_gcn,
                                 b_gcn, deg, acc12);

  // atom embed + residue pooling
  atom_embed<<<GB, B, 0, stream>>>(acc12, xw2, deg, b_gcn, pos, resid, w_ae, b_ae, g_ae,
                                   be_ae, res_acc, res_pacc, res_cnt);

  // residue embed
  res_embed<<<GS, B, 0, stream>>>(res_acc, res_pacc, res_cnt, w_re, b_re, g_re, be_re,
                                  res_x, res_pos);

  // residue PointConv: 4 waves per residue into zeroed x3acc
  rc_pre<<<GS, B, 0, stream>>>(res_x, w_rc, b_rc, rw);
  rc_gather<<<(N_RES * RPW * 64 + B - 1) / B, B, 0, stream>>>(rw, res_pos, ss_rc, cur_rc,
                                                              w_rc, g_rc, be_rc, x3acc);
  rg_embed<<<GS, B, 0, stream>>>(x3acc, w_rg, b_rg, g_rg, be_rg, x3);

  // loss
  loss_pairs<<<GS, B, 0, stream>>>(x3, src_idx, tgt_idx, y_lab, lacc);
  finalize<<<1, 64, 0, stream>>>(lacc, (float*)d_out);
}